// Round 4
// baseline (607.248 us; speedup 1.0000x reference)
//
#include <hip/hip_runtime.h>
#include <math.h>

#define M_ROWS 32768
#define N_CLS  2048
#define NGRP   8
#define CPG    256
#define NS     10
#define NCAND  16
#define EDIM   400
#define KPAD   416            // 13 * 32, zero-padded
#define NKT    13
#define BK     32
#define SGS    448            // padded group-sum stride (>= lane+384 max 447)
#define NPART  32             // d~ partial sums per row (16 n-tiles x 2 wave-halves)

typedef _Float16 f16x8 __attribute__((ext_vector_type(8)));
typedef float f32x4 __attribute__((ext_vector_type(4)));

__device__ __forceinline__ void gld_lds16(const void* g, void* l) {
    __builtin_amdgcn_global_load_lds(
        (const __attribute__((address_space(1))) unsigned int*)g,
        (__attribute__((address_space(3))) unsigned int*)l, 16, 0, 0);
}

// ---------------- fp32 -> f16 hi (K padded to 416) + row sum-of-squares ----------------
__global__ __launch_bounds__(256) void k_split_hi(const float* __restrict__ in,
                                                  unsigned short* __restrict__ hi,
                                                  float* __restrict__ ss, int rows) {
    int row  = blockIdx.x * 4 + (threadIdx.x >> 6);
    int lane = threadIdx.x & 63;
    if (row >= rows) return;
    const float* src = in + (size_t)row * EDIM;
    unsigned short* ph = hi + (size_t)row * KPAD;
    float s = 0.f;
    #pragma unroll
    for (int q = 0; q < 2; ++q) {
        int c4 = lane + q * 64;
        if (c4 < KPAD / 4) {
            int k = c4 * 4;
            float4 v = make_float4(0.f, 0.f, 0.f, 0.f);
            if (k < EDIM) v = *(const float4*)(src + k);
            float va[4] = {v.x, v.y, v.z, v.w};
            unsigned short ha[4];
            #pragma unroll
            for (int t = 0; t < 4; ++t) {
                float f = va[t];
                _Float16 h = (_Float16)f;
                ha[t] = __builtin_bit_cast(unsigned short, h);
                s = fmaf(f, f, s);
            }
            ushort4 H; H.x = ha[0]; H.y = ha[1]; H.z = ha[2]; H.w = ha[3];
            *(ushort4*)(ph + k) = H;
        }
    }
    #pragma unroll
    for (int o = 32; o; o >>= 1) s += __shfl_xor(s, o, 64);
    if (lane == 0) ss[row] = s;
}

// ---------------- per-group embedding sums: Sg = sum emb (exact), SgH = sum fl16(emb) ----------------
__global__ __launch_bounds__(448) void k_groupsum(const float* __restrict__ emb,
                                                  const unsigned short* __restrict__ ehi,
                                                  float* __restrict__ Sg,
                                                  float* __restrict__ SgH) {
    const int g = blockIdx.x;
    const int t = threadIdx.x;          // 0..447
    float se = 0.f, sh = 0.f;
    if (t < EDIM) {
        for (int j = 0; j < CPG; ++j) {
            se += emb[(size_t)(g * CPG + j) * EDIM + t];
            _Float16 h = __builtin_bit_cast(_Float16, ehi[(size_t)(g * CPG + j) * KPAD + t]);
            sh += (float)h;
        }
    }
    Sg[g * SGS + t]  = se;
    SgH[g * SGS + t] = sh;
}

// ---------------- 1-pass f16 MFMA distance GEMM + d~ row partial sums ----------------
__global__ __launch_bounds__(256, 4) void k_dist1(
    const unsigned short* __restrict__ xhi, const unsigned short* __restrict__ ehi,
    const float* __restrict__ xx, const float* __restrict__ ee,
    float* __restrict__ enc, float* __restrict__ gsum) {
    __shared__ __attribute__((aligned(16))) _Float16 Ah[128][BK];
    __shared__ __attribute__((aligned(16))) _Float16 Bh[128][BK];

    // XCD-chunked swizzle: each XCD owns 32 contiguous M-tiles (3.4 MB of A fits its L2)
    // and iterates all 16 N-tiles. grid = 4096, bijective.
    const int wg    = blockIdx.x;
    const int xcd   = wg & 7;
    const int local = wg >> 3;            // 0..511
    const int mx    = xcd * 32 + (local & 31);
    const int ny    = local >> 5;         // 0..15
    const int m0    = mx * 128;
    const int n0    = ny * 128;

    const int tid  = threadIdx.x;
    const int lane = tid & 63, wid = tid >> 6;
    const int wr = (wid >> 1) * 64, wc = (wid & 1) * 64;
    const int lr = lane & 15, ko = lane >> 4;

    f32x4 acc[4][4];
    #pragma unroll
    for (int i = 0; i < 4; ++i)
        #pragma unroll
        for (int j = 0; j < 4; ++j) { f32x4 z = {0.f, 0.f, 0.f, 0.f}; acc[i][j] = z; }

    for (int kt = 0; kt < NKT; ++kt) {
        const int k0 = kt * BK;
        #pragma unroll
        for (int q = 0; q < 2; ++q) {
            int c = q * 256 + tid;        // 0..511 chunks of 16B per array
            int row = c >> 2, kc = c & 3;
            size_t goA = (size_t)(m0 + row) * KPAD + k0 + kc * 8;
            size_t goB = (size_t)(n0 + row) * KPAD + k0 + kc * 8;
            int loff = (c >> 6) * 1024;   // wave-uniform LDS base
            gld_lds16(xhi + goA, (char*)&Ah[0][0] + loff);
            gld_lds16(ehi + goB, (char*)&Bh[0][0] + loff);
        }
        __syncthreads();

        f16x8 a_h[4];
        #pragma unroll
        for (int i = 0; i < 4; ++i)
            a_h[i] = *(const f16x8*)&Ah[wr + i * 16 + lr][ko * 8];
        #pragma unroll
        for (int j = 0; j < 4; ++j) {
            f16x8 b_h = *(const f16x8*)&Bh[wc + j * 16 + lr][ko * 8];
            #pragma unroll
            for (int i = 0; i < 4; ++i)
                acc[i][j] = __builtin_amdgcn_mfma_f32_16x16x32_f16(a_h[i], b_h, acc[i][j], 0, 0, 0);
        }
        __syncthreads();
    }

    // epilogue: d~ = xx + ee - 2*dot ; enc = 1/d~ ; R2-style per-row 64-col partial sums
    #pragma unroll
    for (int i = 0; i < 4; ++i) {
        #pragma unroll
        for (int r = 0; r < 4; ++r) {
            int row = m0 + wr + i * 16 + ko * 4 + r;
            float xm = xx[row];
            float rs = 0.f;
            #pragma unroll
            for (int j = 0; j < 4; ++j) {
                int col = n0 + wc + j * 16 + lr;
                float dd = fmaf(-2.f, acc[i][j][r], xm + ee[col]);
                rs += dd;
                enc[(size_t)row * N_CLS + col] = 1.0f / dd;
            }
            rs += __shfl_xor(rs, 1, 64);
            rs += __shfl_xor(rs, 2, 64);
            rs += __shfl_xor(rs, 4, 64);
            rs += __shfl_xor(rs, 8, 64);
            if (lr == 0)
                gsum[(size_t)row * NPART + ny * 2 + (wc >> 6)] = rs;
        }
    }
}

// ---------------- per-row: corrected group argmin, approx top-16, exact refine, top-10, gather ----------------
__global__ __launch_bounds__(256) void k_select2(const float* __restrict__ x,
                                                 const float* __restrict__ emb,
                                                 const float* __restrict__ enc,
                                                 const float* __restrict__ gsum,
                                                 const float* __restrict__ Sg,
                                                 const float* __restrict__ SgH,
                                                 const float* __restrict__ xx,
                                                 const float* __restrict__ ee,
                                                 float* __restrict__ out0,
                                                 float* __restrict__ rmse,
                                                 unsigned int* __restrict__ hist) {
    const int wave = threadIdx.x >> 6;
    const int lane = threadIdx.x & 63;
    const int m = blockIdx.x * 4 + wave;

    // x row (and its f16-rounded image) in registers, lane-strided
    const float* xrg = x + (size_t)m * EDIM;
    float xr[7], xh[7];
    #pragma unroll
    for (int k = 0; k < 7; ++k) {
        int d = lane + 64 * k;
        float f = (d < EDIM) ? xrg[d] : 0.f;
        xr[k] = f;
        xh[k] = (float)(_Float16)f;
    }
    const float xm = xx[m];

    // group scores: sum of GEMM d~ partials (R2-identical numerics) + exact correction
    //   sum_j d_j = sum_j d~_j - 2*(x.Sg - x_hi.SgH)
    float aE[NGRP], aH[NGRP];
    #pragma unroll
    for (int g = 0; g < NGRP; ++g) { aE[g] = 0.f; aH[g] = 0.f; }
    #pragma unroll
    for (int k = 0; k < 7; ++k) {
        int d = lane + 64 * k;   // < 448 always; pads are zero
        #pragma unroll
        for (int g = 0; g < NGRP; ++g) {
            aE[g] = fmaf(xr[k], Sg[g * SGS + d], aE[g]);
            aH[g] = fmaf(xh[k], SgH[g * SGS + d], aH[g]);
        }
    }
    const float* gs = gsum + (size_t)m * NPART;
    int bestg = 0; float bestv = 0.f;
    #pragma unroll
    for (int g = 0; g < NGRP; ++g) {
        float sE = aE[g], sH = aH[g];
        #pragma unroll
        for (int o = 1; o < 64; o <<= 1) { sE += __shfl_xor(sE, o, 64); sH += __shfl_xor(sH, o, 64); }
        float base = 0.f;
        #pragma unroll
        for (int p = 0; p < 4; ++p) base += gs[g * 4 + p];
        float sc = fmaf(-2.f, sE - sH, base);
        if (g == 0 || sc < bestv) { bestv = sc; bestg = g; }
    }
    const int j0 = bestg * CPG;

    // approx top-16 candidates from stored 1/d~ (rank10->16 margin >> d~ error)
    const float* pr = enc + (size_t)m * N_CLS + j0;
    float v[4];
    #pragma unroll
    for (int s4 = 0; s4 < 4; ++s4) v[s4] = pr[lane + 64 * s4];

    int cidx[NCAND];
    #pragma unroll
    for (int t = 0; t < NCAND; ++t) {
        float bv = v[0]; int bs = 0;
        #pragma unroll
        for (int s4 = 1; s4 < 4; ++s4) if (v[s4] > bv) { bv = v[s4]; bs = s4; }
        int bidx = lane + 64 * bs;
        #pragma unroll
        for (int o = 1; o < 64; o <<= 1) {
            float ov = __shfl_xor(bv, o, 64);
            int   oi = __shfl_xor(bidx, o, 64);
            if (ov > bv || (ov == bv && oi < bidx)) { bv = ov; bidx = oi; }
        }
        cidx[t] = bidx;
        if ((bidx & 63) == lane) v[bidx >> 6] = -INFINITY;
    }

    // exact fp32 refine of the 16 candidates
    float pv[NCAND];
    #pragma unroll
    for (int t = 0; t < NCAND; ++t) {
        int j = j0 + cidx[t];
        const float* er = emb + (size_t)j * EDIM;
        float a = 0.f;
        #pragma unroll
        for (int k = 0; k < 7; ++k) {
            int d = lane + 64 * k;
            if (d < EDIM) a = fmaf(xr[k], er[d], a);
        }
        #pragma unroll
        for (int o = 1; o < 64; o <<= 1) a += __shfl_xor(a, o, 64);
        float dd = fmaf(-2.f, a, xm + ee[j]);
        pv[t] = 1.0f / dd;
    }

    // top-10 of the 16 refined (desc, ties -> lower local index)
    unsigned used = 0;
    float w[NS]; int gi[NS]; float psum = 0.f;
    #pragma unroll
    for (int t = 0; t < NS; ++t) {
        float bv = 0.f; int bc = -1;
        #pragma unroll
        for (int c = 0; c < NCAND; ++c) {
            if (!((used >> c) & 1u)) {
                if (bc < 0 || pv[c] > bv || (pv[c] == bv && cidx[c] < cidx[bc])) { bv = pv[c]; bc = c; }
            }
        }
        used |= 1u << bc;
        w[t] = bv; gi[t] = j0 + cidx[bc]; psum += fabsf(bv);
    }
    float wn = fmaxf(psum, 1e-12f);
    #pragma unroll
    for (int t = 0; t < NS; ++t) w[t] /= wn;

    if (lane == 0) atomicAdd(&hist[gi[0]], 1u);

    // weighted gather-sum + straight-through + per-row mse partial
    float* orow = out0 + (size_t)m * EDIM;
    float sq = 0.f;
    #pragma unroll
    for (int k = 0; k < 7; ++k) {
        int d = lane + 64 * k;
        if (d < EDIM) {
            float o = 0.f;
            #pragma unroll
            for (int t = 0; t < NS; ++t) o = fmaf(w[t], emb[(size_t)gi[t] * EDIM + d], o);
            float xv = xr[k];
            float diff = xv - o;
            sq = fmaf(diff, diff, sq);
            orow[d] = (o - xv) + xv;
        }
    }
    #pragma unroll
    for (int o = 32; o; o >>= 1) sq += __shfl_xor(sq, o, 64);
    if (lane == 0) rmse[m] = sq;
}

// ---------------- final deterministic reduction: loss + entropy ----------------
__global__ __launch_bounds__(1024) void k_final(const float* __restrict__ rmse,
                                                const unsigned int* __restrict__ hist,
                                                float* __restrict__ loss_out,
                                                float* __restrict__ ent_out) {
    __shared__ float red[1024];
    const int t = threadIdx.x;

    float s = 0.f;
    for (int i = t; i < M_ROWS; i += 1024) s += rmse[i];
    red[t] = s; __syncthreads();
    for (int off = 512; off; off >>= 1) {
        if (t < off) red[t] += red[t + off];
        __syncthreads();
    }
    if (t == 0) {
        float q = red[0] / 13107200.0f;
        loss_out[0] = q + 0.25f * q;
    }
    __syncthreads();

    float e = 0.f;
    for (int i = t; i < N_CLS; i += 1024) {
        unsigned int h = hist[i];
        if (h > 0) {
            float prb = (float)h / 32768.0f;
            e -= prb * logf(prb);
        }
    }
    red[t] = e; __syncthreads();
    for (int off = 512; off; off >>= 1) {
        if (t < off) red[t] += red[t + off];
        __syncthreads();
    }
    if (t == 0) ent_out[0] = red[0];
}

extern "C" void kernel_launch(void* const* d_in, const int* in_sizes, int n_in,
                              void* d_out, int out_size, void* d_ws, size_t ws_size,
                              hipStream_t stream) {
    const float* x   = (const float*)d_in[0];   // [32768, 400]
    const float* emb = (const float*)d_in[1];   // [2048, 400]

    float* out      = (float*)d_out;
    float* loss_out = out;
    float* out0     = out + 1;
    float* ent_out  = out + 1 + M_ROWS * EDIM;
    float* enc      = out + 2 + M_ROWS * EDIM;

    float* ws   = (float*)d_ws;
    float* ee   = ws;                                   // [2048]
    float* xx   = ee + N_CLS;                           // [32768]
    float* Sg   = xx + M_ROWS;                          // [8][448]
    float* SgH  = Sg + NGRP * SGS;                      // [8][448]
    float* gsum = SgH + NGRP * SGS;                     // [32768][32]
    float* rmse = gsum + (size_t)M_ROWS * NPART;        // [32768]
    unsigned int* hist = (unsigned int*)(rmse + M_ROWS);// [2048]
    float* fend = rmse + M_ROWS + N_CLS;

    unsigned short* xhi = (unsigned short*)fend;        // [32768][416]
    unsigned short* ehi = xhi + (size_t)M_ROWS * KPAD;  // [2048][416]

    hipMemsetAsync(hist, 0, N_CLS * sizeof(unsigned int), stream);

    k_split_hi<<<M_ROWS / 4, 256, 0, stream>>>(x, xhi, xx, M_ROWS);
    k_split_hi<<<N_CLS / 4, 256, 0, stream>>>(emb, ehi, ee, N_CLS);
    k_groupsum<<<NGRP, 448, 0, stream>>>(emb, ehi, Sg, SgH);

    k_dist1<<<(M_ROWS / 128) * (N_CLS / 128), 256, 0, stream>>>(xhi, ehi, xx, ee, enc, gsum);

    k_select2<<<M_ROWS / 4, 256, 0, stream>>>(x, emb, enc, gsum, Sg, SgH, xx, ee,
                                              out0, rmse, hist);

    k_final<<<1, 1024, 0, stream>>>(rmse, hist, loss_out, ent_out);
}

// Round 5
// 400.736 us; speedup vs baseline: 1.5153x; 1.5153x over previous
//
#include <hip/hip_runtime.h>
#include <math.h>

#define M_ROWS 32768
#define N_CLS  2048
#define NGRP   8
#define CPG    256
#define NS     10
#define NCAND  16
#define EDIM   400
#define KPAD   416            // 13 * 32, zero-padded
#define NKT    13
#define BK     32
#define SGS    448            // padded group-sum stride (>= lane+384 max 447)
#define NPART  32             // d~ partial sums per row (16 n-tiles x 2 wave-halves)

typedef _Float16 f16x8 __attribute__((ext_vector_type(8)));
typedef float f32x4 __attribute__((ext_vector_type(4)));

__device__ __forceinline__ void gld_lds16(const void* g, void* l) {
    __builtin_amdgcn_global_load_lds(
        (const __attribute__((address_space(1))) unsigned int*)g,
        (__attribute__((address_space(3))) unsigned int*)l, 16, 0, 0);
}

// ---------------- fp32 -> f16 hi (K padded to 416) + row sum-of-squares ----------------
__global__ __launch_bounds__(256) void k_split_hi(const float* __restrict__ in,
                                                  unsigned short* __restrict__ hi,
                                                  float* __restrict__ ss, int rows) {
    int row  = blockIdx.x * 4 + (threadIdx.x >> 6);
    int lane = threadIdx.x & 63;
    if (row >= rows) return;
    const float* src = in + (size_t)row * EDIM;
    unsigned short* ph = hi + (size_t)row * KPAD;
    float s = 0.f;
    #pragma unroll
    for (int q = 0; q < 2; ++q) {
        int c4 = lane + q * 64;
        if (c4 < KPAD / 4) {
            int k = c4 * 4;
            float4 v = make_float4(0.f, 0.f, 0.f, 0.f);
            if (k < EDIM) v = *(const float4*)(src + k);
            float va[4] = {v.x, v.y, v.z, v.w};
            unsigned short ha[4];
            #pragma unroll
            for (int t = 0; t < 4; ++t) {
                float f = va[t];
                _Float16 h = (_Float16)f;
                ha[t] = __builtin_bit_cast(unsigned short, h);
                s = fmaf(f, f, s);
            }
            ushort4 H; H.x = ha[0]; H.y = ha[1]; H.z = ha[2]; H.w = ha[3];
            *(ushort4*)(ph + k) = H;
        }
    }
    #pragma unroll
    for (int o = 32; o; o >>= 1) s += __shfl_xor(s, o, 64);
    if (lane == 0) ss[row] = s;
}

// ---------------- per-group embedding sums: Sg = sum emb (exact), SgH = sum fl16(emb) ----------------
__global__ __launch_bounds__(448) void k_groupsum(const float* __restrict__ emb,
                                                  const unsigned short* __restrict__ ehi,
                                                  float* __restrict__ Sg,
                                                  float* __restrict__ SgH) {
    const int g = blockIdx.x;
    const int t = threadIdx.x;          // 0..447
    float se = 0.f, sh = 0.f;
    if (t < EDIM) {
        for (int j = 0; j < CPG; ++j) {
            se += emb[(size_t)(g * CPG + j) * EDIM + t];
            _Float16 h = __builtin_bit_cast(_Float16, ehi[(size_t)(g * CPG + j) * KPAD + t]);
            sh += (float)h;
        }
    }
    Sg[g * SGS + t]  = se;
    SgH[g * SGS + t] = sh;
}

// ---------------- 1-pass f16 MFMA distance GEMM + d~ row partial sums ----------------
__global__ __launch_bounds__(256, 4) void k_dist1(
    const unsigned short* __restrict__ xhi, const unsigned short* __restrict__ ehi,
    const float* __restrict__ xx, const float* __restrict__ ee,
    float* __restrict__ enc, float* __restrict__ gsum) {
    __shared__ __attribute__((aligned(16))) _Float16 Ah[128][BK];
    __shared__ __attribute__((aligned(16))) _Float16 Bh[128][BK];

    const int wg    = blockIdx.x;
    const int xcd   = wg & 7;
    const int local = wg >> 3;            // 0..511
    const int mx    = xcd * 32 + (local & 31);
    const int ny    = local >> 5;         // 0..15
    const int m0    = mx * 128;
    const int n0    = ny * 128;

    const int tid  = threadIdx.x;
    const int lane = tid & 63, wid = tid >> 6;
    const int wr = (wid >> 1) * 64, wc = (wid & 1) * 64;
    const int lr = lane & 15, ko = lane >> 4;

    f32x4 acc[4][4];
    #pragma unroll
    for (int i = 0; i < 4; ++i)
        #pragma unroll
        for (int j = 0; j < 4; ++j) { f32x4 z = {0.f, 0.f, 0.f, 0.f}; acc[i][j] = z; }

    for (int kt = 0; kt < NKT; ++kt) {
        const int k0 = kt * BK;
        #pragma unroll
        for (int q = 0; q < 2; ++q) {
            int c = q * 256 + tid;        // 0..511 chunks of 16B per array
            int row = c >> 2, kc = c & 3;
            size_t goA = (size_t)(m0 + row) * KPAD + k0 + kc * 8;
            size_t goB = (size_t)(n0 + row) * KPAD + k0 + kc * 8;
            int loff = (c >> 6) * 1024;   // wave-uniform LDS base
            gld_lds16(xhi + goA, (char*)&Ah[0][0] + loff);
            gld_lds16(ehi + goB, (char*)&Bh[0][0] + loff);
        }
        __syncthreads();

        f16x8 a_h[4];
        #pragma unroll
        for (int i = 0; i < 4; ++i)
            a_h[i] = *(const f16x8*)&Ah[wr + i * 16 + lr][ko * 8];
        #pragma unroll
        for (int j = 0; j < 4; ++j) {
            f16x8 b_h = *(const f16x8*)&Bh[wc + j * 16 + lr][ko * 8];
            #pragma unroll
            for (int i = 0; i < 4; ++i)
                acc[i][j] = __builtin_amdgcn_mfma_f32_16x16x32_f16(a_h[i], b_h, acc[i][j], 0, 0, 0);
        }
        __syncthreads();
    }

    #pragma unroll
    for (int i = 0; i < 4; ++i) {
        #pragma unroll
        for (int r = 0; r < 4; ++r) {
            int row = m0 + wr + i * 16 + ko * 4 + r;
            float xm = xx[row];
            float rs = 0.f;
            #pragma unroll
            for (int j = 0; j < 4; ++j) {
                int col = n0 + wc + j * 16 + lr;
                float dd = fmaf(-2.f, acc[i][j][r], xm + ee[col]);
                rs += dd;
                enc[(size_t)row * N_CLS + col] = 1.0f / dd;
            }
            rs += __shfl_xor(rs, 1, 64);
            rs += __shfl_xor(rs, 2, 64);
            rs += __shfl_xor(rs, 4, 64);
            rs += __shfl_xor(rs, 8, 64);
            if (lr == 0)
                gsum[(size_t)row * NPART + ny * 2 + (wc >> 6)] = rs;
        }
    }
}

// ---------------- per-row select: lane-distributed, zero runtime-indexed arrays ----------------
__global__ __launch_bounds__(256) void k_select3(const float* __restrict__ x,
                                                 const float* __restrict__ emb,
                                                 const float* __restrict__ enc,
                                                 const float* __restrict__ gsum,
                                                 const float* __restrict__ Sg,
                                                 const float* __restrict__ SgH,
                                                 const float* __restrict__ xx,
                                                 const float* __restrict__ ee,
                                                 float* __restrict__ out0,
                                                 float* __restrict__ rmse,
                                                 unsigned int* __restrict__ hist) {
    __shared__ __attribute__((aligned(16))) float xs[4][EDIM];

    const int wave = threadIdx.x >> 6;
    const int lane = threadIdx.x & 63;
    const int m = blockIdx.x * 4 + wave;

    // x row lane-strided in regs + staged to LDS for the refine phase
    const float* xrg = x + (size_t)m * EDIM;
    float xr[7], xh[7];
    #pragma unroll
    for (int k = 0; k < 7; ++k) {
        int d = lane + 64 * k;
        float f = (d < EDIM) ? xrg[d] : 0.f;
        xr[k] = f;
        xh[k] = (float)(_Float16)f;
        if (d < EDIM) xs[wave][d] = f;
    }
    const float xm = xx[m];

    // group scores: sum of GEMM d~ partials + exact correction -2*(x.Sg - x_hi.SgH)
    float aD[NGRP];
    #pragma unroll
    for (int g = 0; g < NGRP; ++g) aD[g] = 0.f;
    #pragma unroll
    for (int k = 0; k < 7; ++k) {
        int d = lane + 64 * k;   // < 448 always; pads are zero
        #pragma unroll
        for (int g = 0; g < NGRP; ++g) {
            aD[g] = fmaf(xr[k], Sg[g * SGS + d], aD[g]);
            aD[g] = fmaf(-xh[k], SgH[g * SGS + d], aD[g]);
        }
    }
    const float* gs = gsum + (size_t)m * NPART;
    int bestg = 0; float bestv = 0.f;
    #pragma unroll
    for (int g = 0; g < NGRP; ++g) {
        float sD = aD[g];
        #pragma unroll
        for (int o = 1; o < 64; o <<= 1) sD += __shfl_xor(sD, o, 64);
        float base = 0.f;
        #pragma unroll
        for (int p = 0; p < 4; ++p) base += gs[g * 4 + p];
        float sc = fmaf(-2.f, sD, base);
        if (g == 0 || sc < bestv) { bestv = sc; bestg = g; }
    }
    const int j0 = bestg * CPG;

    // ---- Phase A: top-16 candidate set from stored 1/d~ (exact R4 tie semantics) ----
    const float* pr = enc + (size_t)m * N_CLS + j0;
    float v0 = pr[lane], v1 = pr[lane + 64], v2 = pr[lane + 128], v3 = pr[lane + 192];

    int cand = 0;  // lane t (t<16) ends holding the t-th candidate's local col idx
    #pragma unroll
    for (int t = 0; t < NCAND; ++t) {
        float bv = v0; int bs = 0;
        if (v1 > bv) { bv = v1; bs = 1; }
        if (v2 > bv) { bv = v2; bs = 2; }
        if (v3 > bv) { bv = v3; bs = 3; }
        int bidx = lane + 64 * bs;
        #pragma unroll
        for (int o = 1; o < 64; o <<= 1) {
            float ov = __shfl_xor(bv, o, 64);
            int   oi = __shfl_xor(bidx, o, 64);
            if (ov > bv || (ov == bv && oi < bidx)) { bv = ov; bidx = oi; }
        }
        if (lane == t) cand = bidx;
        bool me = (bidx & 63) == lane;
        int  sl = bidx >> 6;
        v0 = (me && sl == 0) ? -INFINITY : v0;
        v1 = (me && sl == 1) ? -INFINITY : v1;
        v2 = (me && sl == 2) ? -INFINITY : v2;
        v3 = (me && sl == 3) ? -INFINITY : v3;
    }

    // ---- Phase B: exact fp32 refine, 4 lanes per candidate ----
    int cj = __shfl(cand, lane >> 2, 64);          // candidate (lane>>2)'s local idx
    int jg = j0 + cj;
    const float4* er4 = (const float4*)(emb + (size_t)jg * EDIM);
    const float4* xs4 = (const float4*)(&xs[wave][0]);
    float a = 0.f;
    #pragma unroll
    for (int q = 0; q < 25; ++q) {
        int idx = (lane & 3) + 4 * q;              // 0..99
        float4 e = er4[idx];
        float4 xv = xs4[idx];
        a = fmaf(xv.x, e.x, a);
        a = fmaf(xv.y, e.y, a);
        a = fmaf(xv.z, e.z, a);
        a = fmaf(xv.w, e.w, a);
    }
    a += __shfl_xor(a, 1, 64);
    a += __shfl_xor(a, 2, 64);
    float dd = fmaf(-2.f, a, xm + ee[jg]);
    float pvq = 1.0f / dd;
    // redistribute: lane l (l<16) gets candidate l's refined prob from lane 4l
    float pcur = __shfl(pvq, (lane & 15) * 4, 64);
    if (lane >= NCAND) pcur = -INFINITY;
    int ccur = cand;                               // local col idx (valid lanes 0..15)

    // ---- Phase C: top-10 of 16 via 16-lane tournament (ties -> lower local idx) ----
    float wsel = 0.f; int gsel = 0;
    #pragma unroll
    for (int t = 0; t < NS; ++t) {
        float bv = pcur; int bc = ccur; int bl = lane;
        #pragma unroll
        for (int o = 1; o < 16; o <<= 1) {
            float ov = __shfl_xor(bv, o, 64);
            int   oc = __shfl_xor(bc, o, 64);
            int   ol = __shfl_xor(bl, o, 64);
            if (ov > bv || (ov == bv && oc < bc)) { bv = ov; bc = oc; bl = ol; }
        }
        if (lane == bl) pcur = -INFINITY;          // kill winner (bl uniform in group 0)
        if (lane == t) { wsel = bv; gsel = j0 + bc; }
    }

    // psum over the 10 winners (lanes 0..9)
    float ps = (lane < NS) ? fabsf(wsel) : 0.f;
    #pragma unroll
    for (int o = 1; o < 16; o <<= 1) ps += __shfl_xor(ps, o, 64);
    float wn = fmaxf(__shfl(ps, 0, 64), 1e-12f);

    if (lane == 0) atomicAdd(&hist[gsel], 1u);     // lane 0 holds top-1

    // ---- Phase D: weighted gather-sum + straight-through + mse ----
    float wt[NS]; int gt[NS];
    #pragma unroll
    for (int t = 0; t < NS; ++t) {
        wt[t] = __shfl(wsel, t, 64) / wn;
        gt[t] = __shfl(gsel, t, 64);
    }
    float* orow = out0 + (size_t)m * EDIM;
    float sq = 0.f;
    #pragma unroll
    for (int k = 0; k < 7; ++k) {
        int d = lane + 64 * k;
        if (d < EDIM) {
            float o = 0.f;
            #pragma unroll
            for (int t = 0; t < NS; ++t) o = fmaf(wt[t], emb[(size_t)gt[t] * EDIM + d], o);
            float xv = xr[k];
            float diff = xv - o;
            sq = fmaf(diff, diff, sq);
            orow[d] = (o - xv) + xv;
        }
    }
    #pragma unroll
    for (int o = 32; o; o >>= 1) sq += __shfl_xor(sq, o, 64);
    if (lane == 0) rmse[m] = sq;
}

// ---------------- final deterministic reduction: loss + entropy ----------------
__global__ __launch_bounds__(1024) void k_final(const float* __restrict__ rmse,
                                                const unsigned int* __restrict__ hist,
                                                float* __restrict__ loss_out,
                                                float* __restrict__ ent_out) {
    __shared__ float red[1024];
    const int t = threadIdx.x;

    float s = 0.f;
    for (int i = t; i < M_ROWS; i += 1024) s += rmse[i];
    red[t] = s; __syncthreads();
    for (int off = 512; off; off >>= 1) {
        if (t < off) red[t] += red[t + off];
        __syncthreads();
    }
    if (t == 0) {
        float q = red[0] / 13107200.0f;
        loss_out[0] = q + 0.25f * q;
    }
    __syncthreads();

    float e = 0.f;
    for (int i = t; i < N_CLS; i += 1024) {
        unsigned int h = hist[i];
        if (h > 0) {
            float prb = (float)h / 32768.0f;
            e -= prb * logf(prb);
        }
    }
    red[t] = e; __syncthreads();
    for (int off = 512; off; off >>= 1) {
        if (t < off) red[t] += red[t + off];
        __syncthreads();
    }
    if (t == 0) ent_out[0] = red[0];
}

extern "C" void kernel_launch(void* const* d_in, const int* in_sizes, int n_in,
                              void* d_out, int out_size, void* d_ws, size_t ws_size,
                              hipStream_t stream) {
    const float* x   = (const float*)d_in[0];   // [32768, 400]
    const float* emb = (const float*)d_in[1];   // [2048, 400]

    float* out      = (float*)d_out;
    float* loss_out = out;
    float* out0     = out + 1;
    float* ent_out  = out + 1 + M_ROWS * EDIM;
    float* enc      = out + 2 + M_ROWS * EDIM;

    float* ws   = (float*)d_ws;
    float* ee   = ws;                                   // [2048]
    float* xx   = ee + N_CLS;                           // [32768]
    float* Sg   = xx + M_ROWS;                          // [8][448]
    float* SgH  = Sg + NGRP * SGS;                      // [8][448]
    float* gsum = SgH + NGRP * SGS;                     // [32768][32]
    float* rmse = gsum + (size_t)M_ROWS * NPART;        // [32768]
    unsigned int* hist = (unsigned int*)(rmse + M_ROWS);// [2048]
    float* fend = rmse + M_ROWS + N_CLS;

    unsigned short* xhi = (unsigned short*)fend;        // [32768][416]
    unsigned short* ehi = xhi + (size_t)M_ROWS * KPAD;  // [2048][416]

    hipMemsetAsync(hist, 0, N_CLS * sizeof(unsigned int), stream);

    k_split_hi<<<M_ROWS / 4, 256, 0, stream>>>(x, xhi, xx, M_ROWS);
    k_split_hi<<<N_CLS / 4, 256, 0, stream>>>(emb, ehi, ee, N_CLS);
    k_groupsum<<<NGRP, 448, 0, stream>>>(emb, ehi, Sg, SgH);

    k_dist1<<<(M_ROWS / 128) * (N_CLS / 128), 256, 0, stream>>>(xhi, ehi, xx, ee, enc, gsum);

    k_select3<<<M_ROWS / 4, 256, 0, stream>>>(x, emb, enc, gsum, Sg, SgH, xx, ee,
                                              out0, rmse, hist);

    k_final<<<1, 1024, 0, stream>>>(rmse, hist, loss_out, ent_out);
}

// Round 6
// 360.014 us; speedup vs baseline: 1.6867x; 1.1131x over previous
//
#include <hip/hip_runtime.h>
#include <math.h>

#define M_ROWS 32768
#define N_CLS  2048
#define NGRP   8
#define CPG    256
#define NS     10
#define NCAND  16
#define EDIM   400
#define KPAD   416            // 13 * 32, zero-padded
#define NKT    13
#define BK     32
#define SGS    448            // padded group-sum stride (>= lane+384 max 447)
#define NPART  32             // d~ partial sums per row (16 n-tiles x 2 wave-halves)

typedef _Float16 f16x8 __attribute__((ext_vector_type(8)));
typedef float f32x4 __attribute__((ext_vector_type(4)));

__device__ __forceinline__ void gld_lds16(const void* g, void* l) {
    __builtin_amdgcn_global_load_lds(
        (const __attribute__((address_space(1))) unsigned int*)g,
        (__attribute__((address_space(3))) unsigned int*)l, 16, 0, 0);
}

// ---------------- fp32 -> f16 hi (K padded to 416) + row sum-of-squares ----------------
__global__ __launch_bounds__(256) void k_split_hi(const float* __restrict__ in,
                                                  unsigned short* __restrict__ hi,
                                                  float* __restrict__ ss, int rows) {
    int row  = blockIdx.x * 4 + (threadIdx.x >> 6);
    int lane = threadIdx.x & 63;
    if (row >= rows) return;
    const float* src = in + (size_t)row * EDIM;
    unsigned short* ph = hi + (size_t)row * KPAD;
    float s = 0.f;
    #pragma unroll
    for (int q = 0; q < 2; ++q) {
        int c4 = lane + q * 64;
        if (c4 < KPAD / 4) {
            int k = c4 * 4;
            float4 v = make_float4(0.f, 0.f, 0.f, 0.f);
            if (k < EDIM) v = *(const float4*)(src + k);
            float va[4] = {v.x, v.y, v.z, v.w};
            unsigned short ha[4];
            #pragma unroll
            for (int t = 0; t < 4; ++t) {
                float f = va[t];
                _Float16 h = (_Float16)f;
                ha[t] = __builtin_bit_cast(unsigned short, h);
                s = fmaf(f, f, s);
            }
            ushort4 H; H.x = ha[0]; H.y = ha[1]; H.z = ha[2]; H.w = ha[3];
            *(ushort4*)(ph + k) = H;
        }
    }
    #pragma unroll
    for (int o = 32; o; o >>= 1) s += __shfl_xor(s, o, 64);
    if (lane == 0) ss[row] = s;
}

// ---------------- per-group embedding sums: Sg = sum emb (exact), SgH = sum fl16(emb) ----------------
__global__ __launch_bounds__(448) void k_groupsum(const float* __restrict__ emb,
                                                  const unsigned short* __restrict__ ehi,
                                                  float* __restrict__ Sg,
                                                  float* __restrict__ SgH) {
    const int g = blockIdx.x;
    const int t = threadIdx.x;          // 0..447
    float se = 0.f, sh = 0.f;
    if (t < EDIM) {
        for (int j = 0; j < CPG; ++j) {
            se += emb[(size_t)(g * CPG + j) * EDIM + t];
            _Float16 h = __builtin_bit_cast(_Float16, ehi[(size_t)(g * CPG + j) * KPAD + t]);
            sh += (float)h;
        }
    }
    Sg[g * SGS + t]  = se;
    SgH[g * SGS + t] = sh;
}

// ---------------- 1-pass f16 MFMA distance GEMM + d~ row partial sums ----------------
__global__ __launch_bounds__(256, 4) void k_dist1(
    const unsigned short* __restrict__ xhi, const unsigned short* __restrict__ ehi,
    const float* __restrict__ xx, const float* __restrict__ ee,
    float* __restrict__ enc, float* __restrict__ gsum) {
    __shared__ __attribute__((aligned(16))) _Float16 Ah[128][BK];
    __shared__ __attribute__((aligned(16))) _Float16 Bh[128][BK];

    const int wg    = blockIdx.x;
    const int xcd   = wg & 7;
    const int local = wg >> 3;            // 0..511
    const int mx    = xcd * 32 + (local & 31);
    const int ny    = local >> 5;         // 0..15
    const int m0    = mx * 128;
    const int n0    = ny * 128;

    const int tid  = threadIdx.x;
    const int lane = tid & 63, wid = tid >> 6;
    const int wr = (wid >> 1) * 64, wc = (wid & 1) * 64;
    const int lr = lane & 15, ko = lane >> 4;

    f32x4 acc[4][4];
    #pragma unroll
    for (int i = 0; i < 4; ++i)
        #pragma unroll
        for (int j = 0; j < 4; ++j) { f32x4 z = {0.f, 0.f, 0.f, 0.f}; acc[i][j] = z; }

    for (int kt = 0; kt < NKT; ++kt) {
        const int k0 = kt * BK;
        #pragma unroll
        for (int q = 0; q < 2; ++q) {
            int c = q * 256 + tid;        // 0..511 chunks of 16B per array
            int row = c >> 2, kc = c & 3;
            size_t goA = (size_t)(m0 + row) * KPAD + k0 + kc * 8;
            size_t goB = (size_t)(n0 + row) * KPAD + k0 + kc * 8;
            int loff = (c >> 6) * 1024;   // wave-uniform LDS base
            gld_lds16(xhi + goA, (char*)&Ah[0][0] + loff);
            gld_lds16(ehi + goB, (char*)&Bh[0][0] + loff);
        }
        __syncthreads();

        f16x8 a_h[4];
        #pragma unroll
        for (int i = 0; i < 4; ++i)
            a_h[i] = *(const f16x8*)&Ah[wr + i * 16 + lr][ko * 8];
        #pragma unroll
        for (int j = 0; j < 4; ++j) {
            f16x8 b_h = *(const f16x8*)&Bh[wc + j * 16 + lr][ko * 8];
            #pragma unroll
            for (int i = 0; i < 4; ++i)
                acc[i][j] = __builtin_amdgcn_mfma_f32_16x16x32_f16(a_h[i], b_h, acc[i][j], 0, 0, 0);
        }
        __syncthreads();
    }

    #pragma unroll
    for (int i = 0; i < 4; ++i) {
        #pragma unroll
        for (int r = 0; r < 4; ++r) {
            int row = m0 + wr + i * 16 + ko * 4 + r;
            float xm = xx[row];
            float rs = 0.f;
            #pragma unroll
            for (int j = 0; j < 4; ++j) {
                int col = n0 + wc + j * 16 + lr;
                float dd = fmaf(-2.f, acc[i][j][r], xm + ee[col]);
                rs += dd;
                enc[(size_t)row * N_CLS + col] = 1.0f / dd;
            }
            rs += __shfl_xor(rs, 1, 64);
            rs += __shfl_xor(rs, 2, 64);
            rs += __shfl_xor(rs, 4, 64);
            rs += __shfl_xor(rs, 8, 64);
            if (lr == 0)
                gsum[(size_t)row * NPART + ny * 2 + (wc >> 6)] = rs;
        }
    }
}

// ---------------- per-row select: DS-minimized (packed keys, bitonic-16, transposed group reduce) ----------------
__global__ __launch_bounds__(256) void k_select4(const float* __restrict__ x,
                                                 const float* __restrict__ emb,
                                                 const float* __restrict__ enc,
                                                 const float* __restrict__ gsum,
                                                 const float* __restrict__ Sg,
                                                 const float* __restrict__ SgH,
                                                 const float* __restrict__ xx,
                                                 const float* __restrict__ ee,
                                                 float* __restrict__ out0,
                                                 float* __restrict__ rmse,
                                                 unsigned int* __restrict__ hist) {
    const int wave = threadIdx.x >> 6;
    const int lane = threadIdx.x & 63;
    const int m = blockIdx.x * 4 + wave;

    // x row lane-strided in regs (no LDS staging; refine reads x from global/L1)
    const float* xrg = x + (size_t)m * EDIM;
    float xr[7], xh[7];
    #pragma unroll
    for (int k = 0; k < 7; ++k) {
        int d = lane + 64 * k;
        float f = (d < EDIM) ? xrg[d] : 0.f;
        xr[k] = f;
        xh[k] = (float)(_Float16)f;
    }
    const float xm = xx[m];

    // ---- group scores: d~ partial sums + exact correction -2*(x.Sg - x_hi.SgH) ----
    float aD[NGRP];
    #pragma unroll
    for (int g = 0; g < NGRP; ++g) aD[g] = 0.f;
    #pragma unroll
    for (int k = 0; k < 7; ++k) {
        int d = lane + 64 * k;   // < 448 always; pads are zero
        #pragma unroll
        for (int g = 0; g < NGRP; ++g) {
            aD[g] = fmaf(xr[k], Sg[g * SGS + d], aD[g]);
            aD[g] = fmaf(-xh[k], SgH[g * SGS + d], aD[g]);
        }
    }
    // class-reduce: lane l ends with partial over lanes == l (mod 8), for every g
    #pragma unroll
    for (int g = 0; g < NGRP; ++g) {
        aD[g] += __shfl_xor(aD[g], 8, 64);
        aD[g] += __shfl_xor(aD[g], 16, 64);
        aD[g] += __shfl_xor(aD[g], 32, 64);
    }
    // lane bits[5:3] select the group; sum its 8 class-partials over bits[2:0]
    const int myg = (lane >> 3) & 7;
    float s = aD[0];
    s = (myg == 1) ? aD[1] : s;
    s = (myg == 2) ? aD[2] : s;
    s = (myg == 3) ? aD[3] : s;
    s = (myg == 4) ? aD[4] : s;
    s = (myg == 5) ? aD[5] : s;
    s = (myg == 6) ? aD[6] : s;
    s = (myg == 7) ? aD[7] : s;
    s += __shfl_xor(s, 1, 64);
    s += __shfl_xor(s, 2, 64);
    s += __shfl_xor(s, 4, 64);
    const float* gs = gsum + (size_t)m * NPART;
    float base = gs[myg * 4 + 0] + gs[myg * 4 + 1] + gs[myg * 4 + 2] + gs[myg * 4 + 3];
    float sc = fmaf(-2.f, s, base);
    // 8-way argmin (ties -> lowest g), butterfly over the group-holder bits
    int bg = myg; float bv = sc;
    #pragma unroll
    for (int o = 8; o < 64; o <<= 1) {
        float ov = __shfl_xor(bv, o, 64);
        int   og = __shfl_xor(bg, o, 64);
        if (ov < bv || (ov == bv && og < bg)) { bv = ov; bg = og; }
    }
    const int j0 = bg * CPG;

    // ---- Phase A: top-16 candidates via packed u32 keys (val | inverted idx) ----
    const float* pr = enc + (size_t)m * N_CLS + j0;
    float4 pv4 = *(const float4*)(pr + lane * 4);
    unsigned key0 = (__float_as_uint(pv4.x) & 0xFFFFFF00u) | (255u - (unsigned)(lane * 4 + 0));
    unsigned key1 = (__float_as_uint(pv4.y) & 0xFFFFFF00u) | (255u - (unsigned)(lane * 4 + 1));
    unsigned key2 = (__float_as_uint(pv4.z) & 0xFFFFFF00u) | (255u - (unsigned)(lane * 4 + 2));
    unsigned key3 = (__float_as_uint(pv4.w) & 0xFFFFFF00u) | (255u - (unsigned)(lane * 4 + 3));

    unsigned candKey = 0;
    #pragma unroll
    for (int t = 0; t < NCAND; ++t) {
        unsigned a01 = key0 > key1 ? key0 : key1;
        unsigned a23 = key2 > key3 ? key2 : key3;
        unsigned mk  = a01 > a23 ? a01 : a23;
        #pragma unroll
        for (int o = 1; o < 64; o <<= 1) {
            unsigned ok = (unsigned)__shfl_xor((int)mk, o, 64);
            mk = ok > mk ? ok : mk;
        }
        if (lane == t) candKey = mk;
        unsigned widx = 255u - (mk & 0xFFu);
        if ((widx >> 2) == (unsigned)lane) {
            unsigned slot = widx & 3u;
            key0 = (slot == 0u) ? 0u : key0;
            key1 = (slot == 1u) ? 0u : key1;
            key2 = (slot == 2u) ? 0u : key2;
            key3 = (slot == 3u) ? 0u : key3;
        }
    }
    int cand = 255 - (int)(candKey & 0xFFu);   // valid on lanes 0..15

    // ---- Phase B: exact fp32 refine, 4 lanes per candidate (x from global/L1) ----
    int cj = __shfl(cand, lane >> 2, 64);
    int jg = j0 + cj;
    const float4* er4 = (const float4*)(emb + (size_t)jg * EDIM);
    const float4* xs4 = (const float4*)xrg;
    float a = 0.f;
    #pragma unroll
    for (int q = 0; q < 25; ++q) {
        int idx = (lane & 3) + 4 * q;              // 0..99
        float4 e = er4[idx];
        float4 xv = xs4[idx];
        a = fmaf(xv.x, e.x, a);
        a = fmaf(xv.y, e.y, a);
        a = fmaf(xv.z, e.z, a);
        a = fmaf(xv.w, e.w, a);
    }
    a += __shfl_xor(a, 1, 64);
    a += __shfl_xor(a, 2, 64);
    float dd = fmaf(-2.f, a, xm + ee[jg]);
    float pvq = 1.0f / dd;
    // replicate the 16 refined (val, idx) pairs into every 16-lane group
    float pcur = __shfl(pvq, (lane & 15) * 4, 64);
    int   ccur = __shfl(cand, lane & 15, 64);

    // ---- Phase C: bitonic sort-16 desc by (pv, -cidx); lane t -> t-th ranked ----
    const int l16 = lane & 15;
    #pragma unroll
    for (int k = 2; k <= 16; k <<= 1) {
        #pragma unroll
        for (int j = k >> 1; j > 0; j >>= 1) {
            float opv = __shfl_xor(pcur, j, 16);
            int   occ = __shfl_xor(ccur, j, 16);
            bool amLow     = (l16 & j) == 0;
            bool blockDesc = (l16 & k) == 0;
            bool iGreater  = (pcur > opv) || (pcur == opv && ccur < occ);
            bool keep = (amLow == blockDesc) ? iGreater : !iGreater;
            if (!keep) { pcur = opv; ccur = occ; }
        }
    }

    // L1 norm over the 10 winners (all values positive)
    float ps = (l16 < NS) ? pcur : 0.f;
    ps += __shfl_xor(ps, 1, 16);
    ps += __shfl_xor(ps, 2, 16);
    ps += __shfl_xor(ps, 4, 16);
    ps += __shfl_xor(ps, 8, 16);
    float wn = fmaxf(ps, 1e-12f);

    if (lane == 0) atomicAdd(&hist[j0 + ccur], 1u);   // lane 0 = top-1

    // ---- Phase D: weighted gather-sum + straight-through + mse ----
    float wt[NS]; int gt[NS];
    #pragma unroll
    for (int t = 0; t < NS; ++t) {
        wt[t] = __shfl(pcur, t, 16) / wn;
        gt[t] = j0 + __shfl(ccur, t, 16);
    }
    float* orow = out0 + (size_t)m * EDIM;
    float sq = 0.f;
    #pragma unroll
    for (int k = 0; k < 7; ++k) {
        int d = lane + 64 * k;
        if (d < EDIM) {
            float o = 0.f;
            #pragma unroll
            for (int t = 0; t < NS; ++t) o = fmaf(wt[t], emb[(size_t)gt[t] * EDIM + d], o);
            float xv = xr[k];
            float diff = xv - o;
            sq = fmaf(diff, diff, sq);
            orow[d] = (o - xv) + xv;
        }
    }
    #pragma unroll
    for (int o = 32; o; o >>= 1) sq += __shfl_xor(sq, o, 64);
    if (lane == 0) rmse[m] = sq;
}

// ---------------- final deterministic reduction: loss + entropy ----------------
__global__ __launch_bounds__(1024) void k_final(const float* __restrict__ rmse,
                                                const unsigned int* __restrict__ hist,
                                                float* __restrict__ loss_out,
                                                float* __restrict__ ent_out) {
    __shared__ float red[1024];
    const int t = threadIdx.x;

    float s = 0.f;
    for (int i = t; i < M_ROWS; i += 1024) s += rmse[i];
    red[t] = s; __syncthreads();
    for (int off = 512; off; off >>= 1) {
        if (t < off) red[t] += red[t + off];
        __syncthreads();
    }
    if (t == 0) {
        float q = red[0] / 13107200.0f;
        loss_out[0] = q + 0.25f * q;
    }
    __syncthreads();

    float e = 0.f;
    for (int i = t; i < N_CLS; i += 1024) {
        unsigned int h = hist[i];
        if (h > 0) {
            float prb = (float)h / 32768.0f;
            e -= prb * logf(prb);
        }
    }
    red[t] = e; __syncthreads();
    for (int off = 512; off; off >>= 1) {
        if (t < off) red[t] += red[t + off];
        __syncthreads();
    }
    if (t == 0) ent_out[0] = red[0];
}

extern "C" void kernel_launch(void* const* d_in, const int* in_sizes, int n_in,
                              void* d_out, int out_size, void* d_ws, size_t ws_size,
                              hipStream_t stream) {
    const float* x   = (const float*)d_in[0];   // [32768, 400]
    const float* emb = (const float*)d_in[1];   // [2048, 400]

    float* out      = (float*)d_out;
    float* loss_out = out;
    float* out0     = out + 1;
    float* ent_out  = out + 1 + M_ROWS * EDIM;
    float* enc      = out + 2 + M_ROWS * EDIM;

    float* ws   = (float*)d_ws;
    float* ee   = ws;                                   // [2048]
    float* xx   = ee + N_CLS;                           // [32768]
    float* Sg   = xx + M_ROWS;                          // [8][448]
    float* SgH  = Sg + NGRP * SGS;                      // [8][448]
    float* gsum = SgH + NGRP * SGS;                     // [32768][32]
    float* rmse = gsum + (size_t)M_ROWS * NPART;        // [32768]
    unsigned int* hist = (unsigned int*)(rmse + M_ROWS);// [2048]
    float* fend = rmse + M_ROWS + N_CLS;

    unsigned short* xhi = (unsigned short*)fend;        // [32768][416]
    unsigned short* ehi = xhi + (size_t)M_ROWS * KPAD;  // [2048][416]

    hipMemsetAsync(hist, 0, N_CLS * sizeof(unsigned int), stream);

    k_split_hi<<<M_ROWS / 4, 256, 0, stream>>>(x, xhi, xx, M_ROWS);
    k_split_hi<<<N_CLS / 4, 256, 0, stream>>>(emb, ehi, ee, N_CLS);
    k_groupsum<<<NGRP, 448, 0, stream>>>(emb, ehi, Sg, SgH);

    k_dist1<<<(M_ROWS / 128) * (N_CLS / 128), 256, 0, stream>>>(xhi, ehi, xx, ee, enc, gsum);

    k_select4<<<M_ROWS / 4, 256, 0, stream>>>(x, emb, enc, gsum, Sg, SgH, xx, ee,
                                              out0, rmse, hist);

    k_final<<<1, 1024, 0, stream>>>(rmse, hist, loss_out, ent_out);
}

// Round 8
// 347.878 us; speedup vs baseline: 1.7456x; 1.0349x over previous
//
#include <hip/hip_runtime.h>
#include <math.h>

#define M_ROWS 32768
#define N_CLS  2048
#define NGRP   8
#define CPG    256
#define NS     10
#define NCAND  16
#define EDIM   400
#define KPAD   416            // 13 * 32, zero-padded
#define NKT    13
#define BK     32
#define SGS    448            // padded group-sum stride (>= lane+384 max 447)
#define NPART  32             // d~ partial sums per row (16 n-tiles x 2 wave-halves)

typedef _Float16 f16x8 __attribute__((ext_vector_type(8)));
typedef float f32x4 __attribute__((ext_vector_type(4)));

__device__ __forceinline__ void gld_lds16(const void* g, void* l) {
    __builtin_amdgcn_global_load_lds(
        (const __attribute__((address_space(1))) unsigned int*)g,
        (__attribute__((address_space(3))) unsigned int*)l, 16, 0, 0);
}

// ---- DPP cross-lane helpers (VALU pipe, no DS): xor1 = quad_perm[1,0,3,2],
// ---- xor2 = quad_perm[2,3,0,1], xor8 = row_ror:8 (within row-of-16, +8 mod 16 == ^8)
#define DPP_X1 0xB1
#define DPP_X2 0x4E
#define DPP_X8 0x128

template <int CTRL>
__device__ __forceinline__ int dpp_i(int v) {
    return __builtin_amdgcn_update_dpp(v, v, CTRL, 0xF, 0xF, true);
}
template <int CTRL>
__device__ __forceinline__ float dpp_f(float v) {
    return __builtin_bit_cast(float,
        __builtin_amdgcn_update_dpp(__builtin_bit_cast(int, v),
                                    __builtin_bit_cast(int, v), CTRL, 0xF, 0xF, true));
}
template <int J>
__device__ __forceinline__ float xch_f(float v) {
    if constexpr (J == 1) return dpp_f<DPP_X1>(v);
    else if constexpr (J == 2) return dpp_f<DPP_X2>(v);
    else if constexpr (J == 8) return dpp_f<DPP_X8>(v);
    else return __shfl_xor(v, J, 64);
}
template <int J>
__device__ __forceinline__ int xch_i(int v) {
    if constexpr (J == 1) return dpp_i<DPP_X1>(v);
    else if constexpr (J == 2) return dpp_i<DPP_X2>(v);
    else if constexpr (J == 8) return dpp_i<DPP_X8>(v);
    else return __shfl_xor(v, J, 64);
}

// ---------------- fp32 -> f16 hi (K padded to 416) + row sum-of-squares ----------------
__global__ __launch_bounds__(256) void k_split_hi(const float* __restrict__ in,
                                                  unsigned short* __restrict__ hi,
                                                  float* __restrict__ ss, int rows) {
    int row  = blockIdx.x * 4 + (threadIdx.x >> 6);
    int lane = threadIdx.x & 63;
    if (row >= rows) return;
    const float* src = in + (size_t)row * EDIM;
    unsigned short* ph = hi + (size_t)row * KPAD;
    float s = 0.f;
    #pragma unroll
    for (int q = 0; q < 2; ++q) {
        int c4 = lane + q * 64;
        if (c4 < KPAD / 4) {
            int k = c4 * 4;
            float4 v = make_float4(0.f, 0.f, 0.f, 0.f);
            if (k < EDIM) v = *(const float4*)(src + k);
            float va[4] = {v.x, v.y, v.z, v.w};
            unsigned short ha[4];
            #pragma unroll
            for (int t = 0; t < 4; ++t) {
                float f = va[t];
                _Float16 h = (_Float16)f;
                ha[t] = __builtin_bit_cast(unsigned short, h);
                s = fmaf(f, f, s);
            }
            ushort4 H; H.x = ha[0]; H.y = ha[1]; H.z = ha[2]; H.w = ha[3];
            *(ushort4*)(ph + k) = H;
        }
    }
    #pragma unroll
    for (int o = 32; o; o >>= 1) s += __shfl_xor(s, o, 64);
    if (lane == 0) ss[row] = s;
}

// ---------------- per-group embedding sums: Sg = sum emb (exact), SgH = sum fl16(emb) ----------------
__global__ __launch_bounds__(448) void k_groupsum(const float* __restrict__ emb,
                                                  const unsigned short* __restrict__ ehi,
                                                  float* __restrict__ Sg,
                                                  float* __restrict__ SgH) {
    const int g = blockIdx.x;
    const int t = threadIdx.x;          // 0..447
    float se = 0.f, sh = 0.f;
    if (t < EDIM) {
        for (int j = 0; j < CPG; ++j) {
            se += emb[(size_t)(g * CPG + j) * EDIM + t];
            _Float16 h = __builtin_bit_cast(_Float16, ehi[(size_t)(g * CPG + j) * KPAD + t]);
            sh += (float)h;
        }
    }
    Sg[g * SGS + t]  = se;
    SgH[g * SGS + t] = sh;
}

// ---------------- 1-pass f16 MFMA distance GEMM, 2-phase pipelined ----------------
// Sync points are single asm blocks with "memory" clobbers: raw s_barrier is NOT a
// compiler memory fence (LLVM IntrNoMem) — R7's race was next-tile global_load_lds
// calls hoisted above the end-of-iteration barrier, overwriting LDS other waves
// were still reading. Fused waitcnt+barrier leaves no reordering window.
__global__ __launch_bounds__(256, 4) void k_dist1(
    const unsigned short* __restrict__ xhi, const unsigned short* __restrict__ ehi,
    const float* __restrict__ xx, const float* __restrict__ ee,
    float* __restrict__ enc, float* __restrict__ gsum) {
    __shared__ __attribute__((aligned(16))) _Float16 Ah[2][128][BK];
    __shared__ __attribute__((aligned(16))) _Float16 Bh[2][128][BK];

    const int wg    = blockIdx.x;
    const int xcd   = wg & 7;
    const int local = wg >> 3;            // 0..511
    const int mx    = xcd * 32 + (local & 31);
    const int ny    = local >> 5;         // 0..15
    const int m0    = mx * 128;
    const int n0    = ny * 128;

    const int tid  = threadIdx.x;
    const int lane = tid & 63, wid = tid >> 6;
    const int wr = (wid >> 1) * 64, wc = (wid & 1) * 64;
    const int lr = lane & 15, ko = lane >> 4;

    // stage tile kt into LDS buffer b: 4 gld_lds per thread (counted by vmcnt)
    auto stage = [&](int b, int kt) {
        const int k0 = kt * BK;
        #pragma unroll
        for (int q = 0; q < 2; ++q) {
            int cc = q * 256 + tid;       // 0..511 chunks of 16B per array
            int rw = cc >> 2, kc = cc & 3;
            size_t goA = (size_t)(m0 + rw) * KPAD + k0 + kc * 8;
            size_t goB = (size_t)(n0 + rw) * KPAD + k0 + kc * 8;
            int loff = (cc >> 6) * 1024;  // wave-uniform LDS base
            gld_lds16(xhi + goA, (char*)&Ah[b][0][0] + loff);
            gld_lds16(ehi + goB, (char*)&Bh[b][0][0] + loff);
        }
    };

    f32x4 acc[4][4];
    #pragma unroll
    for (int i = 0; i < 4; ++i)
        #pragma unroll
        for (int j = 0; j < 4; ++j) { f32x4 z = {0.f, 0.f, 0.f, 0.f}; acc[i][j] = z; }

    stage(0, 0);
    for (int kt = 0; kt < NKT; ++kt) {
        const int cur = kt & 1;
        if (kt + 1 < NKT) {
            stage(cur ^ 1, kt + 1);       // 4 more loads in flight
            // wait current tile's 4 loads (leave next tile's 4 in flight) + barrier,
            // fused: no compiler reordering window between wait and barrier
            asm volatile("s_waitcnt vmcnt(4)\n\ts_barrier" ::: "memory");
        } else {
            asm volatile("s_waitcnt vmcnt(0)\n\ts_barrier" ::: "memory");
        }

        f16x8 a_h[4];
        #pragma unroll
        for (int i = 0; i < 4; ++i)
            a_h[i] = *(const f16x8*)&Ah[cur][wr + i * 16 + lr][ko * 8];
        #pragma unroll
        for (int j = 0; j < 4; ++j) {
            f16x8 b_h = *(const f16x8*)&Bh[cur][wc + j * 16 + lr][ko * 8];
            #pragma unroll
            for (int i = 0; i < 4; ++i)
                acc[i][j] = __builtin_amdgcn_mfma_f32_16x16x32_f16(a_h[i], b_h, acc[i][j], 0, 0, 0);
        }
        // end-of-iteration barrier with memory clobber: next iteration's stage()
        // (which overwrites buf[cur]) cannot be hoisted above it
        asm volatile("s_barrier" ::: "memory");
    }

    #pragma unroll
    for (int i = 0; i < 4; ++i) {
        #pragma unroll
        for (int r = 0; r < 4; ++r) {
            int row = m0 + wr + i * 16 + ko * 4 + r;
            float xm = xx[row];
            float rs = 0.f;
            #pragma unroll
            for (int j = 0; j < 4; ++j) {
                int col = n0 + wc + j * 16 + lr;
                float dd = fmaf(-2.f, acc[i][j][r], xm + ee[col]);
                rs += dd;
                enc[(size_t)row * N_CLS + col] = 1.0f / dd;
            }
            rs += dpp_f<DPP_X1>(rs);
            rs += dpp_f<DPP_X2>(rs);
            rs += __shfl_xor(rs, 4, 64);
            rs += dpp_f<DPP_X8>(rs);
            if (lr == 0)
                gsum[(size_t)row * NPART + ny * 2 + (wc >> 6)] = rs;
        }
    }
}

// ---------------- per-row select: DPP-ified (DS ops halved) ----------------
__global__ __launch_bounds__(256) void k_select5(const float* __restrict__ x,
                                                 const float* __restrict__ emb,
                                                 const float* __restrict__ enc,
                                                 const float* __restrict__ gsum,
                                                 const float* __restrict__ Sg,
                                                 const float* __restrict__ SgH,
                                                 const float* __restrict__ xx,
                                                 const float* __restrict__ ee,
                                                 float* __restrict__ out0,
                                                 float* __restrict__ rmse,
                                                 unsigned int* __restrict__ hist) {
    const int wave = threadIdx.x >> 6;
    const int lane = threadIdx.x & 63;
    const int m = blockIdx.x * 4 + wave;

    const float* xrg = x + (size_t)m * EDIM;
    float xr[7], xh[7];
    #pragma unroll
    for (int k = 0; k < 7; ++k) {
        int d = lane + 64 * k;
        float f = (d < EDIM) ? xrg[d] : 0.f;
        xr[k] = f;
        xh[k] = (float)(_Float16)f;
    }
    const float xm = xx[m];

    // ---- group scores: d~ partial sums + exact correction -2*(x.Sg - x_hi.SgH) ----
    float aD[NGRP];
    #pragma unroll
    for (int g = 0; g < NGRP; ++g) aD[g] = 0.f;
    #pragma unroll
    for (int k = 0; k < 7; ++k) {
        int d = lane + 64 * k;   // < 448 always; pads are zero
        #pragma unroll
        for (int g = 0; g < NGRP; ++g) {
            aD[g] = fmaf(xr[k], Sg[g * SGS + d], aD[g]);
            aD[g] = fmaf(-xh[k], SgH[g * SGS + d], aD[g]);
        }
    }
    // class-reduce (xor 8,16,32): lane l -> partial over lanes == l (mod 8)
    #pragma unroll
    for (int g = 0; g < NGRP; ++g) {
        aD[g] += dpp_f<DPP_X8>(aD[g]);
        aD[g] += __shfl_xor(aD[g], 16, 64);
        aD[g] += __shfl_xor(aD[g], 32, 64);
    }
    const int myg = (lane >> 3) & 7;
    float s = aD[0];
    s = (myg == 1) ? aD[1] : s;
    s = (myg == 2) ? aD[2] : s;
    s = (myg == 3) ? aD[3] : s;
    s = (myg == 4) ? aD[4] : s;
    s = (myg == 5) ? aD[5] : s;
    s = (myg == 6) ? aD[6] : s;
    s = (myg == 7) ? aD[7] : s;
    s += dpp_f<DPP_X1>(s);
    s += dpp_f<DPP_X2>(s);
    s += __shfl_xor(s, 4, 64);
    const float* gs = gsum + (size_t)m * NPART;
    float base = gs[myg * 4 + 0] + gs[myg * 4 + 1] + gs[myg * 4 + 2] + gs[myg * 4 + 3];
    float sc = fmaf(-2.f, s, base);
    // 8-way argmin (ties -> lowest g) over the group-holder bits (xor 8,16,32)
    int bg = myg; float bv = sc;
    {
        float ov = dpp_f<DPP_X8>(bv); int og = dpp_i<DPP_X8>(bg);
        if (ov < bv || (ov == bv && og < bg)) { bv = ov; bg = og; }
    }
    #pragma unroll
    for (int o = 16; o < 64; o <<= 1) {
        float ov = __shfl_xor(bv, o, 64);
        int   og = __shfl_xor(bg, o, 64);
        if (ov < bv || (ov == bv && og < bg)) { bv = ov; bg = og; }
    }
    const int j0 = bg * CPG;

    // ---- Phase A: top-16 candidates via packed u32 keys (val | inverted idx) ----
    const float* pr = enc + (size_t)m * N_CLS + j0;
    float4 pv4 = *(const float4*)(pr + lane * 4);
    unsigned key0 = (__float_as_uint(pv4.x) & 0xFFFFFF00u) | (255u - (unsigned)(lane * 4 + 0));
    unsigned key1 = (__float_as_uint(pv4.y) & 0xFFFFFF00u) | (255u - (unsigned)(lane * 4 + 1));
    unsigned key2 = (__float_as_uint(pv4.z) & 0xFFFFFF00u) | (255u - (unsigned)(lane * 4 + 2));
    unsigned key3 = (__float_as_uint(pv4.w) & 0xFFFFFF00u) | (255u - (unsigned)(lane * 4 + 3));

    unsigned candKey = 0;
    #pragma unroll
    for (int t = 0; t < NCAND; ++t) {
        unsigned a01 = key0 > key1 ? key0 : key1;
        unsigned a23 = key2 > key3 ? key2 : key3;
        unsigned mk  = a01 > a23 ? a01 : a23;
        { unsigned o = (unsigned)dpp_i<DPP_X1>((int)mk); mk = o > mk ? o : mk; }
        { unsigned o = (unsigned)dpp_i<DPP_X2>((int)mk); mk = o > mk ? o : mk; }
        { unsigned o = (unsigned)__shfl_xor((int)mk, 4, 64); mk = o > mk ? o : mk; }
        { unsigned o = (unsigned)dpp_i<DPP_X8>((int)mk); mk = o > mk ? o : mk; }
        { unsigned o = (unsigned)__shfl_xor((int)mk, 16, 64); mk = o > mk ? o : mk; }
        { unsigned o = (unsigned)__shfl_xor((int)mk, 32, 64); mk = o > mk ? o : mk; }
        if (lane == t) candKey = mk;
        unsigned widx = 255u - (mk & 0xFFu);
        if ((widx >> 2) == (unsigned)lane) {
            unsigned slot = widx & 3u;
            key0 = (slot == 0u) ? 0u : key0;
            key1 = (slot == 1u) ? 0u : key1;
            key2 = (slot == 2u) ? 0u : key2;
            key3 = (slot == 3u) ? 0u : key3;
        }
    }
    int cand = 255 - (int)(candKey & 0xFFu);   // valid on lanes 0..15

    // ---- Phase B: exact fp32 refine, 4 lanes per candidate ----
    int cj = __shfl(cand, lane >> 2, 64);
    int jg = j0 + cj;
    const float4* er4 = (const float4*)(emb + (size_t)jg * EDIM);
    const float4* xs4 = (const float4*)xrg;
    float a = 0.f;
    #pragma unroll
    for (int q = 0; q < 25; ++q) {
        int idx = (lane & 3) + 4 * q;              // 0..99
        float4 e = er4[idx];
        float4 xv = xs4[idx];
        a = fmaf(xv.x, e.x, a);
        a = fmaf(xv.y, e.y, a);
        a = fmaf(xv.z, e.z, a);
        a = fmaf(xv.w, e.w, a);
    }
    a += dpp_f<DPP_X1>(a);
    a += dpp_f<DPP_X2>(a);
    float dd = fmaf(-2.f, a, xm + ee[jg]);
    float pvq = 1.0f / dd;
    // replicate the 16 refined (val, idx) pairs into every 16-lane group
    float pcur = __shfl(pvq, (lane & 15) * 4, 64);
    int   ccur = __shfl(cand, lane & 15, 64);

    // ---- Phase C: bitonic sort-16 desc by (pv, -cidx); lane t -> t-th ranked ----
    const int l16 = lane & 15;
#define BSTEP(K_, J_) { \
        float opv = xch_f<J_>(pcur); int occ = xch_i<J_>(ccur); \
        bool amLow     = (l16 & (J_)) == 0; \
        bool blockDesc = (l16 & (K_)) == 0; \
        bool iGreater  = (pcur > opv) || (pcur == opv && ccur < occ); \
        bool keep = (amLow == blockDesc) ? iGreater : !iGreater; \
        if (!keep) { pcur = opv; ccur = occ; } }
    BSTEP(2, 1)
    BSTEP(4, 2) BSTEP(4, 1)
    BSTEP(8, 4) BSTEP(8, 2) BSTEP(8, 1)
    BSTEP(16, 8) BSTEP(16, 4) BSTEP(16, 2) BSTEP(16, 1)
#undef BSTEP

    // L1 norm over the 10 winners (all values positive)
    float ps = (l16 < NS) ? pcur : 0.f;
    ps += dpp_f<DPP_X1>(ps);
    ps += dpp_f<DPP_X2>(ps);
    ps += __shfl_xor(ps, 4, 64);
    ps += dpp_f<DPP_X8>(ps);
    float wn = fmaxf(ps, 1e-12f);

    if (lane == 0) atomicAdd(&hist[j0 + ccur], 1u);   // lane 0 = top-1

    // ---- Phase D: weighted gather-sum + straight-through + mse ----
    float wt[NS]; int gt[NS];
    #pragma unroll
    for (int t = 0; t < NS; ++t) {
        wt[t] = __shfl(pcur, t, 16) / wn;
        gt[t] = j0 + __shfl(ccur, t, 16);
    }
    float* orow = out0 + (size_t)m * EDIM;
    float sq = 0.f;
    #pragma unroll
    for (int k = 0; k < 7; ++k) {
        int d = lane + 64 * k;
        if (d < EDIM) {
            float o = 0.f;
            #pragma unroll
            for (int t = 0; t < NS; ++t) o = fmaf(wt[t], emb[(size_t)gt[t] * EDIM + d], o);
            float xv = xr[k];
            float diff = xv - o;
            sq = fmaf(diff, diff, sq);
            orow[d] = (o - xv) + xv;
        }
    }
    sq += dpp_f<DPP_X1>(sq);
    sq += dpp_f<DPP_X2>(sq);
    sq += __shfl_xor(sq, 4, 64);
    sq += dpp_f<DPP_X8>(sq);
    sq += __shfl_xor(sq, 16, 64);
    sq += __shfl_xor(sq, 32, 64);
    if (lane == 0) rmse[m] = sq;
}

// ---------------- final deterministic reduction: loss + entropy ----------------
__global__ __launch_bounds__(1024) void k_final(const float* __restrict__ rmse,
                                                const unsigned int* __restrict__ hist,
                                                float* __restrict__ loss_out,
                                                float* __restrict__ ent_out) {
    __shared__ float red[1024];
    const int t = threadIdx.x;

    float s = 0.f;
    for (int i = t; i < M_ROWS; i += 1024) s += rmse[i];
    red[t] = s; __syncthreads();
    for (int off = 512; off; off >>= 1) {
        if (t < off) red[t] += red[t + off];
        __syncthreads();
    }
    if (t == 0) {
        float q = red[0] / 13107200.0f;
        loss_out[0] = q + 0.25f * q;
    }
    __syncthreads();

    float e = 0.f;
    for (int i = t; i < N_CLS; i += 1024) {
        unsigned int h = hist[i];
        if (h > 0) {
            float prb = (float)h / 32768.0f;
            e -= prb * logf(prb);
        }
    }
    red[t] = e; __syncthreads();
    for (int off = 512; off; off >>= 1) {
        if (t < off) red[t] += red[t + off];
        __syncthreads();
    }
    if (t == 0) ent_out[0] = red[0];
}

extern "C" void kernel_launch(void* const* d_in, const int* in_sizes, int n_in,
                              void* d_out, int out_size, void* d_ws, size_t ws_size,
                              hipStream_t stream) {
    const float* x   = (const float*)d_in[0];   // [32768, 400]
    const float* emb = (const float*)d_in[1];   // [2048, 400]

    float* out      = (float*)d_out;
    float* loss_out = out;
    float* out0     = out + 1;
    float* ent_out  = out + 1 + M_ROWS * EDIM;
    float* enc      = out + 2 + M_ROWS * EDIM;

    float* ws   = (float*)d_ws;
    float* ee   = ws;                                   // [2048]
    float* xx   = ee + N_CLS;                           // [32768]
    float* Sg   = xx + M_ROWS;                          // [8][448]
    float* SgH  = Sg + NGRP * SGS;                      // [8][448]
    float* gsum = SgH + NGRP * SGS;                     // [32768][32]
    float* rmse = gsum + (size_t)M_ROWS * NPART;        // [32768]
    unsigned int* hist = (unsigned int*)(rmse + M_ROWS);// [2048]
    float* fend = rmse + M_ROWS + N_CLS;

    unsigned short* xhi = (unsigned short*)fend;        // [32768][416]
    unsigned short* ehi = xhi + (size_t)M_ROWS * KPAD;  // [2048][416]

    hipMemsetAsync(hist, 0, N_CLS * sizeof(unsigned int), stream);

    k_split_hi<<<M_ROWS / 4, 256, 0, stream>>>(x, xhi, xx, M_ROWS);
    k_split_hi<<<N_CLS / 4, 256, 0, stream>>>(emb, ehi, ee, N_CLS);
    k_groupsum<<<NGRP, 448, 0, stream>>>(emb, ehi, Sg, SgH);

    k_dist1<<<(M_ROWS / 128) * (N_CLS / 128), 256, 0, stream>>>(xhi, ehi, xx, ee, enc, gsum);

    k_select5<<<M_ROWS / 4, 256, 0, stream>>>(x, emb, enc, gsum, Sg, SgH, xx, ee,
                                              out0, rmse, hist);

    k_final<<<1, 1024, 0, stream>>>(rmse, hist, loss_out, ent_out);
}